// Round 2
// baseline (606.797 us; speedup 1.0000x reference)
//
#include <hip/hip_runtime.h>
#include <cmath>

typedef __bf16 bf16_t;
typedef __bf16 bf16x8 __attribute__((ext_vector_type(8)));
typedef float  f32x4  __attribute__((ext_vector_type(4)));

#define SEQ    2048
#define HID    4096
#define QKV_N  6144
#define NH     32
#define NKV    8
#define HD     128
#define ATT_SCALE 0.08838834764831845f

__device__ __forceinline__ f32x4 mfma16(bf16x8 a, bf16x8 b, f32x4 c) {
  return __builtin_amdgcn_mfma_f32_16x16x32_bf16(a, b, c, 0, 0, 0);
}

__device__ __forceinline__ void gload_lds16(const void* g, void* l) {
  __builtin_amdgcn_global_load_lds(
      (const __attribute__((address_space(1))) void*)g,
      (__attribute__((address_space(3))) void*)l, 16, 0, 0);
}

// ---------------- cast fp32 -> bf16 (vectorized) ----------------
__global__ __launch_bounds__(256) void cast_f32_bf16(
    const float* __restrict__ in, bf16_t* __restrict__ out, int n) {
  int i = (blockIdx.x * 256 + threadIdx.x) * 8;
  if (i >= n) return;
  float4 v0 = *(const float4*)(in + i);
  float4 v1 = *(const float4*)(in + i + 4);
  bf16x8 o;
  o[0] = (bf16_t)v0.x; o[1] = (bf16_t)v0.y; o[2] = (bf16_t)v0.z; o[3] = (bf16_t)v0.w;
  o[4] = (bf16_t)v1.x; o[5] = (bf16_t)v1.y; o[6] = (bf16_t)v1.z; o[7] = (bf16_t)v1.w;
  *(bf16x8*)(out + i) = o;
}

// ---------------- transpose + cast: in [R][C] f32 -> out [C][R] bf16 ----------------
__global__ __launch_bounds__(256) void transpose_cast(
    const float* __restrict__ in, bf16_t* __restrict__ out, int R, int C) {
  __shared__ float tile[32][33];
  int c0 = blockIdx.x * 32, r0 = blockIdx.y * 32;
  int x = threadIdx.x, y = threadIdx.y;   // 32 x 8
  for (int j = 0; j < 32; j += 8)
    tile[y + j][x] = in[(size_t)(r0 + y + j) * C + c0 + x];
  __syncthreads();
  for (int j = 0; j < 32; j += 8)
    out[(size_t)(c0 + y + j) * R + r0 + x] = (bf16_t)tile[x][y + j];
}

// ---------------- transpose V part of qkv (bf16): [s][5120+dcol] -> vt[dcol][s] ----------------
__global__ __launch_bounds__(256) void transpose_v(
    const bf16_t* __restrict__ qkv, bf16_t* __restrict__ vt) {
  __shared__ bf16_t tile[32][33];
  int c0 = blockIdx.x * 32, r0 = blockIdx.y * 32;  // c0: dcol, r0: s
  int x = threadIdx.x, y = threadIdx.y;
  for (int j = 0; j < 32; j += 8)
    tile[y + j][x] = qkv[(size_t)(r0 + y + j) * QKV_N + 5120 + c0 + x];
  __syncthreads();
  for (int j = 0; j < 32; j += 8)
    vt[(size_t)(c0 + y + j) * SEQ + r0 + x] = tile[x][y + j];
}

// ---------------- RoPE cos/sin tables ----------------
__global__ __launch_bounds__(256) void rope_tables(
    const int* __restrict__ pos, float* __restrict__ ct, float* __restrict__ st) {
  int idx = blockIdx.x * 256 + threadIdx.x;
  if (idx >= SEQ * 64) return;
  int s = idx >> 6, j = idx & 63;
  double inv = exp(-((double)(2 * j) / 128.0) * log(10000.0));
  double a = (double)pos[s] * inv;
  ct[idx] = (float)cos(a);
  st[idx] = (float)sin(a);
}

// ---------------- apply RoPE in-place to q,k columns of qkv ----------------
__global__ __launch_bounds__(256) void rope_apply(
    bf16_t* __restrict__ qkv, const float* __restrict__ ct, const float* __restrict__ st) {
  int idx = blockIdx.x * 256 + threadIdx.x;   // SEQ * 2560
  int s = idx / 2560, p = idx % 2560;
  int head = p >> 6, j = p & 63;              // heads 0..31 = q, 32..39 = k
  int base = (head < NH) ? head * HD : HID + (head - NH) * HD;
  size_t o1 = (size_t)s * QKV_N + base + j;
  float x1 = (float)qkv[o1], x2 = (float)qkv[o1 + 64];
  float c = ct[s * 64 + j], sn = st[s * 64 + j];
  qkv[o1]      = (bf16_t)(x1 * c - x2 * sn);
  qkv[o1 + 64] = (bf16_t)(x2 * c + x1 * sn);
}

// ---------------- GEMM: C[M][N] = A[M][K] * Bt[N][K]^T  (m97 structure) ----------------
template <typename OutT>
__global__ __launch_bounds__(256, 2) void gemm_bt(
    const bf16_t* __restrict__ A, const bf16_t* __restrict__ Bt,
    OutT* __restrict__ C, int M, int N, int K) {
  __shared__ bf16_t As[128 * 32];
  __shared__ bf16_t Bs[128 * 32];
  const int tid = threadIdx.x;
  const int wid = tid >> 6, lane = tid & 63;
  const int m0 = blockIdx.y * 128, n0 = blockIdx.x * 128;
  const int wr = (wid >> 1) * 64, wc = (wid & 1) * 64;
  const int lrow = lane & 15, lk = lane >> 4;
  f32x4 acc[4][4];
  for (int m = 0; m < 4; ++m)
    for (int n = 0; n < 4; ++n) acc[m][n] = f32x4{0.f, 0.f, 0.f, 0.f};

  for (int k0 = 0; k0 < K; k0 += 32) {
    for (int i = 0; i < 2; ++i) {
      int off = wid * 2048 + i * 1024 + lane * 16;  // byte offset in 8KB tile
      int row = off >> 6;                            // 64B per row (32 bf16)
      int kk = (off & 63) >> 1;                      // element col
      gload_lds16(A + (size_t)(m0 + row) * K + k0 + kk,
                  (char*)As + wid * 2048 + i * 1024);
      gload_lds16(Bt + (size_t)(n0 + row) * K + k0 + kk,
                  (char*)Bs + wid * 2048 + i * 1024);
    }
    __syncthreads();
    bf16x8 a[4], b[4];
    for (int m = 0; m < 4; ++m)
      a[m] = *(const bf16x8*)(As + (wr + m * 16 + lrow) * 32 + lk * 8);
    for (int n = 0; n < 4; ++n)
      b[n] = *(const bf16x8*)(Bs + (wc + n * 16 + lrow) * 32 + lk * 8);
    for (int m = 0; m < 4; ++m)
      for (int n = 0; n < 4; ++n)
        acc[m][n] = mfma16(a[m], b[n], acc[m][n]);
    __syncthreads();
  }
  for (int m = 0; m < 4; ++m)
    for (int n = 0; n < 4; ++n)
      for (int r = 0; r < 4; ++r) {
        int row = m0 + wr + m * 16 + lk * 4 + r;
        int col = n0 + wc + n * 16 + lrow;
        C[(size_t)row * N + col] = (OutT)acc[m][n][r];
      }
}

// ---------------- flash attention (causal, GQA) ----------------
// grid: (NH, SEQ/128); block: 256 (4 waves, 32 q-rows each)
__global__ __launch_bounds__(256) void flash_attn(
    const bf16_t* __restrict__ qkv, const bf16_t* __restrict__ vt,
    bf16_t* __restrict__ attn_out) {
  __shared__ bf16_t Ks[64 * 128];    // [kv][d], swizzled, 16KB
  __shared__ bf16_t Vs[128 * 64];    // [d][kv], swizzled, 16KB
  __shared__ bf16_t Ps[4][32 * 64];  // per-wave P, swizzled, 16KB
  const int h = blockIdx.x, qb = blockIdx.y;
  const int q0 = qb * 128, kvh = h >> 2;
  const int tid = threadIdx.x, wid = tid >> 6, lane = tid & 63;
  const int lrow = lane & 15, lk = lane >> 4;

  // Q in registers: wave rows q0 + wid*32 .. +31
  bf16x8 qreg[2][4];
  for (int m = 0; m < 2; ++m) {
    int qr = q0 + wid * 32 + m * 16 + lrow;
    for (int kd = 0; kd < 4; ++kd)
      qreg[m][kd] =
          *(const bf16x8*)(qkv + (size_t)qr * QKV_N + h * HD + kd * 32 + lk * 8);
  }

  f32x4 acc[2][8];
  float mst[2][4], lst[2][4];
  for (int m = 0; m < 2; ++m) {
    for (int df = 0; df < 8; ++df) acc[m][df] = f32x4{0.f, 0.f, 0.f, 0.f};
    for (int r = 0; r < 4; ++r) { mst[m][r] = -1e30f; lst[m][r] = 0.f; }
  }

  const int ntiles = (q0 + 128) / 64;
  for (int t = 0; t < ntiles; ++t) {
    const int kv0 = t * 64;
    __syncthreads();
    // stage K tile [64][128] (swizzled rows of 256B)
    for (int rnd = 0; rnd < 4; ++rnd) {
      int ch = rnd * 256 + tid, r = ch >> 4, c = ch & 15;
      bf16x8 v = *(const bf16x8*)(qkv + (size_t)(kv0 + r) * QKV_N + HID +
                                  kvh * HD + c * 8);
      *(bf16x8*)((char*)Ks + ((r * 256 + c * 16) ^ ((r & 7) << 4))) = v;
    }
    // stage V^T tile [128][64] (swizzled rows of 128B)
    for (int rnd = 0; rnd < 4; ++rnd) {
      int ch = rnd * 256 + tid, d = ch >> 3, c = ch & 7;
      bf16x8 v =
          *(const bf16x8*)(vt + (size_t)(kvh * HD + d) * SEQ + kv0 + c * 8);
      *(bf16x8*)((char*)Vs + ((d * 128 + c * 16) ^ ((d & 7) << 4))) = v;
    }
    __syncthreads();

    // S = Q K^T   (per wave: 32 q x 64 kv)
    f32x4 s[2][4];
    for (int m = 0; m < 2; ++m)
      for (int n = 0; n < 4; ++n) s[m][n] = f32x4{0.f, 0.f, 0.f, 0.f};
    for (int kd = 0; kd < 4; ++kd) {
      bf16x8 kf[4];
      for (int n = 0; n < 4; ++n) {
        int kr = n * 16 + lrow;
        kf[n] = *(const bf16x8*)((char*)Ks +
                                 ((kr * 256 + kd * 64 + lk * 16) ^ ((kr & 7) << 4)));
      }
      for (int m = 0; m < 2; ++m)
        for (int n = 0; n < 4; ++n)
          s[m][n] = mfma16(qreg[m][kd], kf[n], s[m][n]);
    }

    // online softmax with causal mask
    for (int m = 0; m < 2; ++m) {
      int qrow = q0 + wid * 32 + m * 16 + lk * 4;
      for (int r = 0; r < 4; ++r) {
        int qg = qrow + r;
        float mx = -1e30f;
        for (int n = 0; n < 4; ++n) {
          float val = s[m][n][r] * ATT_SCALE;
          if (kv0 + n * 16 + lrow > qg) val = -1e30f;
          s[m][n][r] = val;
          mx = fmaxf(mx, val);
        }
        for (int off = 1; off < 16; off <<= 1) mx = fmaxf(mx, __shfl_xor(mx, off));
        float mnew = fmaxf(mst[m][r], mx);
        float alpha = __expf(mst[m][r] - mnew);
        float rs = 0.f;
        for (int n = 0; n < 4; ++n) {
          float p = __expf(s[m][n][r] - mnew);
          s[m][n][r] = p;
          rs += p;
        }
        for (int off = 1; off < 16; off <<= 1) rs += __shfl_xor(rs, off);
        lst[m][r] = lst[m][r] * alpha + rs;
        mst[m][r] = mnew;
        for (int df = 0; df < 8; ++df) acc[m][df][r] *= alpha;
      }
    }

    // write P (bf16) to wave-private LDS, swizzled [32][64]
    bf16_t* ps = &Ps[wid][0];
    for (int m = 0; m < 2; ++m)
      for (int n = 0; n < 4; ++n)
        for (int r = 0; r < 4; ++r) {
          int row = m * 16 + lk * 4 + r, col = n * 16 + lrow;
          *(bf16_t*)((char*)ps + ((row * 128 + col * 2) ^ ((row & 7) << 4))) =
              (bf16_t)s[m][n][r];
        }

    // O += P * V
    for (int kc = 0; kc < 2; ++kc) {
      bf16x8 pa[2];
      for (int m = 0; m < 2; ++m) {
        int row = m * 16 + lrow;
        pa[m] = *(const bf16x8*)((char*)ps +
                                 ((row * 128 + kc * 64 + lk * 16) ^ ((row & 7) << 4)));
      }
      for (int df = 0; df < 8; ++df) {
        int d = df * 16 + lrow;
        bf16x8 vb = *(const bf16x8*)((char*)Vs +
                                     ((d * 128 + kc * 64 + lk * 16) ^ ((d & 7) << 4)));
        for (int m = 0; m < 2; ++m) acc[m][df] = mfma16(pa[m], vb, acc[m][df]);
      }
    }
  }

  // epilogue: O /= l, write bf16
  for (int m = 0; m < 2; ++m)
    for (int r = 0; r < 4; ++r) {
      float inv = 1.f / lst[m][r];
      int row = q0 + wid * 32 + m * 16 + lk * 4 + r;
      for (int df = 0; df < 8; ++df) {
        int col = h * HD + df * 16 + lrow;
        attn_out[(size_t)row * HID + col] = (bf16_t)(acc[m][df][r] * inv);
      }
    }
}

// ---------------- launch ----------------
extern "C" void kernel_launch(void* const* d_in, const int* in_sizes, int n_in,
                              void* d_out, int out_size, void* d_ws, size_t ws_size,
                              hipStream_t stream) {
  const int*   positions = (const int*)d_in[0];
  const float* hs        = (const float*)d_in[1];
  const float* wqkv      = (const float*)d_in[2];
  const float* wo        = (const float*)d_in[3];
  float*       out       = (float*)d_out;
  char* ws = (char*)d_ws;

  bf16_t* hsb   = (bf16_t*)(ws + 0);                 // 16,777,216
  bf16_t* wqkvt = (bf16_t*)(ws + 16777216);          // 50,331,648  [6144][4096]
  bf16_t* wot   = (bf16_t*)(ws + 67108864);          // 33,554,432  [4096][4096]
  bf16_t* qkv   = (bf16_t*)(ws + 100663296);         // 25,165,824  [2048][6144]
  float*  ct    = (float*)(ws + 125829120);          // 524,288
  float*  st    = (float*)(ws + 126353408);          // 524,288
  bf16_t* vtb   = (bf16_t*)(ws + 126877696);         // 4,194,304   [1024][2048]
  bf16_t* attn  = (bf16_t*)(ws + 131072000);         // 16,777,216  [2048][4096]

  cast_f32_bf16<<<4096, 256, 0, stream>>>(hs, hsb, SEQ * HID);
  transpose_cast<<<dim3(192, 128), dim3(32, 8), 0, stream>>>(wqkv, wqkvt, HID, QKV_N);
  transpose_cast<<<dim3(128, 128), dim3(32, 8), 0, stream>>>(wo, wot, HID, HID);
  rope_tables<<<512, 256, 0, stream>>>(positions, ct, st);

  gemm_bt<bf16_t><<<dim3(48, 16), 256, 0, stream>>>(hsb, wqkvt, qkv, SEQ, QKV_N, HID);

  rope_apply<<<20480, 256, 0, stream>>>(qkv, ct, st);
  transpose_v<<<dim3(32, 64), dim3(32, 8), 0, stream>>>(qkv, vtb);

  flash_attn<<<dim3(NH, SEQ / 128), 256, 0, stream>>>(qkv, vtb, attn);

  gemm_bt<float><<<dim3(32, 16), 256, 0, stream>>>(attn, wot, out, SEQ, HID, HID);
}